// Round 19
// baseline (283.904 us; speedup 1.0000x reference)
//
#include <hip/hip_runtime.h>
#include <math.h>

#define BG   200
#define NPGc 512
#define EPGc 8192
#define NE   (BG*EPGc)     // 1638400
#define N0   (BG*NPGc)     // 102400
#define FINc 11
#define Hc   128
#define K1c  256
#define K2c  205
#define K3c  164
#define N1   (BG*K1c)      // 51200
#define N2   (BG*K2c)      // 41000
#define N3   (BG*K3c)      // 32800

typedef float f32x4 __attribute__((ext_vector_type(4)));
typedef short s16x8 __attribute__((ext_vector_type(8)));

#define PL ((size_t)N1*Hc)      // hpS/aggS plane stride (elements)
#define PA ((size_t)N0*32)      // conv1 A-plane stride (elements)

// ---- 3-way RNE bf16 split: v = p0 + p1 + p2 + O(2^-24 |v|) -----------------
__device__ inline unsigned short bf16_rne(float v){
  unsigned u = __float_as_uint(v);
  unsigned r = u + 0x7FFFu + ((u >> 16) & 1u);
  return (unsigned short)(r >> 16);
}
__device__ inline float bf16_f32(unsigned short h){
  return __uint_as_float(((unsigned)h) << 16);
}
__device__ inline void split3(float v, unsigned short& r0, unsigned short& r1,
                              unsigned short& r2){
  r0 = bf16_rne(v); float v1 = v - bf16_f32(r0);
  r1 = bf16_rne(v1); float v2 = v1 - bf16_f32(r1);
  r2 = bf16_rne(v2);
}

// fragment-native layout, K=128: (row,k) -> [row>>4][k>>3][row&15][k&7]
__device__ inline size_t flIdx(int row, int k){
  return ((size_t)(row >> 4))*2048 + (size_t)(k >> 3)*128
       + (size_t)(row & 15)*8 + (size_t)(k & 7);
}
// same, K=32 (tile = 512 elems)
__device__ inline size_t flIdx32(int row, int k){
  return ((size_t)(row >> 4))*512 + (size_t)(k >> 3)*128
       + (size_t)(row & 15)*8 + (size_t)(k & 7);
}

// ---------------- front kernel: CSR build + weight prep + x pack -------------
__launch_bounds__(512)
__global__ void k_front(const int* __restrict__ esrc, const int* __restrict__ edst,
                        const float* __restrict__ x,
                        const float* __restrict__ Wrel1, const float* __restrict__ Wroot1,
                        const float* __restrict__ Wrel2, const float* __restrict__ Wroot2,
                        const float* __restrict__ Wrel3, const float* __restrict__ Wroot3,
                        const float* __restrict__ Wl1, const float* __restrict__ Wl2,
                        const float* __restrict__ pw1, const float* __restrict__ pw2,
                        const float* __restrict__ pw3,
                        int* __restrict__ deg, int* __restrict__ rowptr,
                        int* __restrict__ csr, float* __restrict__ xp,
                        float* __restrict__ Wl1T, float* __restrict__ Wl2T,
                        unsigned short* __restrict__ Wsp, unsigned short* __restrict__ W1S,
                        float* __restrict__ z, float* __restrict__ norms){
  int b = blockIdx.x, t = threadIdx.x;
  if (b < BG){
    __shared__ int ed[EPGc];    // 32 KB
    __shared__ int cnt[NPGc];
    __shared__ int sc[NPGc];
    int g = b;
    cnt[t] = 0;
    __syncthreads();
    int gb = g*EPGc;
    for (int i=t; i<EPGc; i+=512){
      int dl = edst[gb+i] & (NPGc-1);
      ed[i] = dl;
      atomicAdd(&cnt[dl], 1);
    }
    __syncthreads();
    int d = cnt[t];
    sc[t] = d;
    __syncthreads();
    for (int o=1;o<NPGc;o<<=1){
      int v = (t>=o) ? sc[t-o] : 0;
      __syncthreads();
      sc[t] += v;
      __syncthreads();
    }
    deg[g*NPGc+t]    = d;
    rowptr[g*NPGc+t] = gb + sc[t] - d;
    cnt[t] = sc[t] - d;
    __syncthreads();
    for (int i=t; i<EPGc; i+=512){
      int p = atomicAdd(&cnt[ed[i]], 1);
      csr[gb+p] = esrc[gb+i];
    }
  } else if (b < 456){
    int idx = (b-200)*512 + t;     // 0..131071
    if (idx < 256*512){
      int f = idx >> 9, tt = idx & 511;
      Wl1T[idx] = Wl1[tt*256 + f];
    }
    if (idx < 512*64){
      int f = idx >> 6, tt = idx & 63;
      Wl2T[idx] = Wl2[tt*512 + f];
    }
    if (idx < 65536){
      int L = idx >> 15, p = (idx >> 14) & 1, ck = idx & 16383;
      int c = ck >> 7, k = ck & 127;
      const float* W = L ? (p ? Wroot3 : Wrel3) : (p ? Wroot2 : Wrel2);
      unsigned short r0, r1, r2;
      split3(W[c*128 + k], r0, r1, r2);
      unsigned short* base = Wsp + (size_t)((L*2+p)*3)*16384;
      size_t fl = flIdx(c, k);
      base[fl]          = r0;
      base[16384 + fl]  = r1;
      base[32768 + fl]  = r2;
    }
    if (idx < 4096){
      int c = idx >> 5, k = idx & 31;
      float v = (k < 11) ? Wrel1[c*11 + k] : (k < 22 ? Wroot1[c*11 + (k-11)] : 0.f);
      unsigned short r0, r1, r2;
      split3(v, r0, r1, r2);
      size_t fl = flIdx32(c, k);
      W1S[fl]        = r0;
      W1S[4096 + fl] = r1;
      W1S[8192 + fl] = r2;
    }
    if (idx < BG*256) z[idx] = 0.f;
    if (b == 455){
      int w = t >> 6, lane = t & 63;
      if (w < 3){
        const float* pw = (w==0) ? pw1 : (w==1 ? pw2 : pw3);
        float v0 = pw[lane], v1 = pw[64+lane];
        float ss = v0*v0 + v1*v1;
        for (int o=32;o>0;o>>=1) ss += __shfl_xor(ss, o);
        if (lane == 0) norms[w] = sqrtf(ss);
      }
    }
  } else {
    int idx = (b-456)*512 + t;     // 0..N0*16-1
    int n = idx >> 4, f = idx & 15;
    xp[idx] = (f < FINc) ? x[n*FINc + f] : 0.f;
  }
}

// ---------------- layer 1: wave per dst, deep load batches, fused split ------
__launch_bounds__(256, 8)
__global__ void k_agg1s(const float* __restrict__ xp, const int* __restrict__ csr,
                        const int* __restrict__ rowptr, const int* __restrict__ deg,
                        unsigned short* __restrict__ AS){
  int bid = (int)((blockIdx.x & 7)*3200 + (blockIdx.x >> 3));
  int d = bid*4 + (threadIdx.x >> 6);
  if (d >= N0) return;
  int lane = threadIdx.x & 63;
  int slot = lane >> 4, f = lane & 15;
  int rs = rowptr[d], dg = deg[d];
  float a0 = 0.f, a1 = 0.f, a2 = 0.f, a3 = 0.f;
  for (int base=0; base<dg; base+=64){
    int e = base + lane;
    int s = 0;
    if (e < dg) s = csr[rs+e];
    int cnt = min(64, dg-base);
    int sv[16];
    #pragma unroll
    for (int u=0; u<16; u++) sv[u] = __shfl(s, u*4 + slot);
    #pragma unroll
    for (int u=0; u<16; u++){
      int ei = u*4 + slot;
      float v = 0.f;
      if (ei < cnt) v = xp[(sv[u] << 4) + f];
      if      ((u & 3) == 0) a0 += v;
      else if ((u & 3) == 1) a1 += v;
      else if ((u & 3) == 2) a2 += v;
      else                   a3 += v;
    }
  }
  a0 = (a0 + a1) + (a2 + a3);
  a0 += __shfl_xor(a0, 16);
  a0 += __shfl_xor(a0, 32);            // all lanes hold agg[f], f = lane&15
  int k0 = 2*lane, k1 = k0 + 1;
  float s0 = __shfl(a0, k0 & 15);
  float s1 = __shfl(a0, k1 & 15);
  if (lane < 16){
    float v0 = (k0 < 11) ? s0 : ((k0 < 22) ? xp[(d<<4) + k0 - 11] : 0.f);
    float v1 = (k1 < 11) ? s1 : ((k1 < 22) ? xp[(d<<4) + k1 - 11] : 0.f);
    unsigned short a_0,a_1,a_2,b_0,b_1,b_2;
    split3(v0, a_0, a_1, a_2);
    split3(v1, b_0, b_1, b_2);
    size_t fl = flIdx32(d, k0);
    *(unsigned*)&AS[fl]        = (unsigned)a_0 | ((unsigned)b_0 << 16);
    *(unsigned*)&AS[PA + fl]   = (unsigned)a_1 | ((unsigned)b_1 << 16);
    *(unsigned*)&AS[2*PA + fl] = (unsigned)a_2 | ((unsigned)b_2 << 16);
  }
}

// ---------------- conv1: 6-term split MFMA, K=32, fused score ---------------
__launch_bounds__(256)
__global__ void k_conv1m(const unsigned short* __restrict__ AS,
                         const unsigned short* __restrict__ W1S,
                         const float* __restrict__ bias, const float* __restrict__ pw,
                         const float* __restrict__ norm_p,
                         float* __restrict__ hout, float* __restrict__ score, int M){
  __shared__ float scds[64][2];
  int tid = threadIdx.x;
  int w = tid >> 6, l = tid & 63;
  int wm = w >> 1, wn = w & 1;
  int lr = l & 15, lk = l >> 4;
  int m0 = blockIdx.x * 64;

  f32x4 acc[2][4];
  #pragma unroll
  for (int mi=0;mi<2;mi++)
    #pragma unroll
    for (int ni=0;ni<4;ni++) acc[mi][ni] = (f32x4){0.f,0.f,0.f,0.f};

  s16x8 af[3][2], bf[3][4];
  #pragma unroll
  for (int mi=0; mi<2; mi++){
    int tile = (m0 + wm*32 + mi*16) >> 4;
    size_t idx = (size_t)tile*512 + (size_t)lk*128 + (size_t)lr*8;
    af[0][mi] = *(const s16x8*)&AS[idx];
    af[1][mi] = *(const s16x8*)&AS[PA + idx];
    af[2][mi] = *(const s16x8*)&AS[2*PA + idx];
  }
  #pragma unroll
  for (int ni=0; ni<4; ni++){
    int ct = wn*4 + ni;
    size_t idx = (size_t)ct*512 + (size_t)lk*128 + (size_t)lr*8;
    bf[0][ni] = *(const s16x8*)&W1S[idx];
    bf[1][ni] = *(const s16x8*)&W1S[4096 + idx];
    bf[2][ni] = *(const s16x8*)&W1S[8192 + idx];
  }
  #define TRM(sa,sb) \
    _Pragma("unroll") \
    for (int ni=0; ni<4; ni++){ \
      _Pragma("unroll") \
      for (int mi=0; mi<2; mi++){ \
        acc[mi][ni] = __builtin_amdgcn_mfma_f32_16x16x32_bf16(af[sa][mi], bf[sb][ni], acc[mi][ni], 0,0,0); \
      } \
    }
  TRM(0,0) TRM(0,1) TRM(1,0) TRM(1,1) TRM(0,2) TRM(2,0)
  #undef TRM

  float nrm = *norm_p;
  float pwv[4], biasv[4];
  #pragma unroll
  for (int ni=0;ni<4;ni++){
    int col = wn*64 + ni*16 + lr;
    pwv[ni] = pw[col]; biasv[ni] = bias[col];
  }
  #pragma unroll
  for (int mi=0; mi<2; mi++){
    #pragma unroll
    for (int reg=0; reg<4; reg++){
      int rl = wm*32 + mi*16 + lk*4 + reg;
      int row = m0 + rl;
      float hv[4]; float sc = 0.f;
      #pragma unroll
      for (int ni=0; ni<4; ni++){
        hv[ni] = fmaxf(acc[mi][ni][reg] + biasv[ni], 0.f);
        sc += hv[ni]*pwv[ni];
      }
      if (row < M){
        #pragma unroll
        for (int ni=0; ni<4; ni++)
          hout[(size_t)row*Hc + wn*64 + ni*16 + lr] = hv[ni];
      }
      sc += __shfl_xor(sc,1); sc += __shfl_xor(sc,2);
      sc += __shfl_xor(sc,4); sc += __shfl_xor(sc,8);
      if (lr == 0) scds[rl][wn] = sc;
    }
  }
  __syncthreads();
  if (tid < 64){
    int row = m0 + tid;
    if (row < M) score[row] = tanhf((scds[tid][0] + scds[tid][1]) / nrm);
  }
}

// ---------------- sort-only kernel: topk + maps + sorted scores --------------
// NP2 threads; hybrid register/LDS bitonic (identical comparator).
template<int N, int K, int NP2>
__launch_bounds__(NP2)
__global__ void k_sortk(const float* __restrict__ score, int* __restrict__ newid,
                        int* __restrict__ perm,
                        const int* __restrict__ map1In, int* __restrict__ map2Out,
                        const int* __restrict__ origPrev, int* __restrict__ origOut,
                        float* __restrict__ svg){
  __shared__ float sv[NP2];
  __shared__ int   si[NP2];
  __shared__ int   nid[N];
  int g = blockIdx.x, t = threadIdx.x;

  float v = (t < N) ? score[g*N + t] : -INFINITY;
  int ix = t;

  for (int k=2;k<=NP2;k<<=1){
    for (int j=k>>1;j>0;j>>=1){
      if (j >= 64){
        sv[t] = v; si[t] = ix;
        __syncthreads();
        int p = t ^ j;
        float vp = sv[p]; int ip = si[p];
        bool pre = (v > vp) || (v == vp && ix < ip);
        bool up = ((t & k) == 0);
        bool lower = ((t & j) == 0);
        bool keep = lower ? (pre == up) : (pre != up);
        if (!keep){ v = vp; ix = ip; }
        __syncthreads();
      } else {
        float vp = __shfl_xor(v, j);
        int   ip = __shfl_xor(ix, j);
        bool pre = (v > vp) || (v == vp && ix < ip);
        bool up = ((t & k) == 0);
        bool lower = ((t & j) == 0);
        bool keep = lower ? (pre == up) : (pre != up);
        if (!keep){ v = vp; ix = ip; }
      }
    }
  }
  sv[t] = v; si[t] = ix;
  __syncthreads();

  if (t < N) nid[si[t]] = (t < K) ? t : -1;
  __syncthreads();
  if (t < N) newid[g*N + t] = (nid[t] >= 0) ? g*K + nid[t] : -1;
  if (t < K){
    perm[g*K + t] = g*N + si[t];
    svg[g*K + t]  = sv[t];
    if (origOut) origOut[g*K + t] = origPrev[g*N + si[t]];
  }
  if (map2Out){
    for (int o = t; o < NPGc; o += NP2){
      int m = map1In[g*NPGc + o];
      int r = (m >= 0) ? nid[m - g*N] : -1;
      map2Out[g*NPGc + o] = (r >= 0) ? g*K + r : -1;
    }
  }
}

// ---------------- gather + split + readout (single instantiation) ------------
// 1024 thr = 16 row-groups x 64 col-pairs; 2-row software pipeline.
__launch_bounds__(1024)
__global__ void k_gath(const float* __restrict__ h, const int* __restrict__ perm,
                       const float* __restrict__ svg, float* __restrict__ hp,
                       unsigned short* __restrict__ hpS, float* __restrict__ z,
                       int K, int doSplit){
  __shared__ float2 smx2[16][64];
  __shared__ float2 ssm2[16][64];
  int g = blockIdx.x, t = threadIdx.x;
  int rg = t >> 6, j2 = t & 63;
  float mx = -INFINITY, my = -INFINITY, sx = 0.f, sy = 0.f;
  for (int r0 = rg; r0 < K; r0 += 32){
    int r1 = r0 + 16;
    bool has1 = (r1 < K);
    int m0 = g*K + r0;
    int m1 = g*K + (has1 ? r1 : r0);
    int row0 = perm[m0];
    int row1 = perm[m1];
    float s0 = svg[m0];
    float s1 = svg[m1];
    float2 v0 = *(const float2*)&h[(size_t)row0*Hc + 2*j2];
    float2 v1 = *(const float2*)&h[(size_t)row1*Hc + 2*j2];
    v0.x *= s0; v0.y *= s0;
    v1.x *= s1; v1.y *= s1;
    if (hp) *(float2*)&hp[(size_t)m0*Hc + 2*j2] = v0;
    if (doSplit){
      unsigned short a0,a1,a2,b0,b1,b2;
      split3(v0.x, a0, a1, a2);
      split3(v0.y, b0, b1, b2);
      size_t fl = flIdx(m0, 2*j2);
      *(unsigned*)&hpS[fl]        = (unsigned)a0 | ((unsigned)b0 << 16);
      *(unsigned*)&hpS[PL + fl]   = (unsigned)a1 | ((unsigned)b1 << 16);
      *(unsigned*)&hpS[2*PL + fl] = (unsigned)a2 | ((unsigned)b2 << 16);
    }
    mx = fmaxf(mx, v0.x); my = fmaxf(my, v0.y); sx += v0.x; sy += v0.y;
    if (has1){
      if (hp) *(float2*)&hp[(size_t)m1*Hc + 2*j2] = v1;
      if (doSplit){
        unsigned short a0,a1,a2,b0,b1,b2;
        split3(v1.x, a0, a1, a2);
        split3(v1.y, b0, b1, b2);
        size_t fl = flIdx(m1, 2*j2);
        *(unsigned*)&hpS[fl]        = (unsigned)a0 | ((unsigned)b0 << 16);
        *(unsigned*)&hpS[PL + fl]   = (unsigned)a1 | ((unsigned)b1 << 16);
        *(unsigned*)&hpS[2*PL + fl] = (unsigned)a2 | ((unsigned)b2 << 16);
      }
      mx = fmaxf(mx, v1.x); my = fmaxf(my, v1.y); sx += v1.x; sy += v1.y;
    }
  }
  smx2[rg][j2] = make_float2(mx, my);
  ssm2[rg][j2] = make_float2(sx, sy);
  __syncthreads();
  if (t < 64){
    float2 M = smx2[0][t], S = ssm2[0][t];
    #pragma unroll
    for (int u=1; u<16; u++){
      float2 m2 = smx2[u][t], s2 = ssm2[u][t];
      M.x = fmaxf(M.x, m2.x); M.y = fmaxf(M.y, m2.y);
      S.x += s2.x; S.y += s2.y;
    }
    int c0 = 2*t, c1 = 2*t + 1;
    z[g*256 + c0]       += M.x;
    z[g*256 + c1]       += M.y;
    z[g*256 + 128 + c0] += S.x / (float)K;
    z[g*256 + 128 + c1] += S.y / (float)K;
  }
}

// ---------------- layers 2/3 aggregation: compact list, 8 chains -------------
__launch_bounds__(256, 4)
__global__ void k_aggHs(const int* __restrict__ orig, const int* __restrict__ map,
                        const float* __restrict__ hp,
                        const int* __restrict__ csr, const int* __restrict__ rowptr,
                        const int* __restrict__ deg, unsigned short* __restrict__ aggS,
                        int M){
  int cpx = gridDim.x >> 3;
  int bid = (int)((blockIdx.x & 7)*cpx + (blockIdx.x >> 3));
  int m = bid*4 + (threadIdx.x>>6);
  int lane = threadIdx.x & 63;
  if (m >= M) return;
  int d = orig[m];
  int rs = rowptr[d], dg = deg[d];
  int half = lane >> 5, cl = lane & 31;
  f32x4 acc[8];
  #pragma unroll
  for (int u=0;u<8;u++) acc[u] = (f32x4){0.f,0.f,0.f,0.f};
  for (int base=0; base<dg; base+=64){
    int e = base + lane;
    int ns = -1;
    if (e < dg){ int s = csr[rs+e]; ns = map[s]; }
    int cnt = min(64, dg-base);
    for (int jj=0; jj<cnt; jj+=16){
      #pragma unroll
      for (int u=0; u<8; u++){
        int ei = jj + u*2 + half;
        int nsj = __shfl(ns, ei & 63);
        if (ei < cnt && nsj >= 0){
          acc[u] += *(const f32x4*)(hp + (size_t)nsj*Hc + cl*4);
        }
      }
    }
  }
  f32x4 s4 = ((acc[0]+acc[1]) + (acc[2]+acc[3])) + ((acc[4]+acc[5]) + (acc[6]+acc[7]));
  #pragma unroll
  for (int i=0;i<4;i++) s4[i] += __shfl_xor(s4[i], 32);
  float e0 = __shfl(s4[0], lane>>1);
  float e1 = __shfl(s4[1], lane>>1);
  float e2 = __shfl(s4[2], lane>>1);
  float e3 = __shfl(s4[3], lane>>1);
  float cx = (lane&1) ? e2 : e0;
  float cy = (lane&1) ? e3 : e1;
  unsigned short x0,x1,x2,y0,y1,y2;
  split3(cx, x0, x1, x2);
  split3(cy, y0, y1, y2);
  size_t fl = flIdx(m, 2*lane);
  *(unsigned*)&aggS[fl]        = (unsigned)x0 | ((unsigned)y0 << 16);
  *(unsigned*)&aggS[PL + fl]   = (unsigned)x1 | ((unsigned)y1 << 16);
  *(unsigned*)&aggS[2*PL + fl] = (unsigned)x2 | ((unsigned)y2 << 16);
}

// ---------------- conv2/conv3: 6-term split MFMA, fused score ----------------
__launch_bounds__(256)
__global__ void k_convH(const unsigned short* __restrict__ A0s,
                        const unsigned short* __restrict__ A1s,
                        const unsigned short* __restrict__ Wsp,
                        const float* __restrict__ bias, const float* __restrict__ pw,
                        const float* __restrict__ norm_p,
                        float* __restrict__ hout, float* __restrict__ score, int M){
  __shared__ float scds[64][2];
  int tid = threadIdx.x;
  int w = tid >> 6, l = tid & 63;
  int wm = w >> 1, wn = w & 1;
  int lr = l & 15, lk = l >> 4;
  int m0 = blockIdx.x * 64;

  f32x4 acc[2][4];
  #pragma unroll
  for (int mi=0;mi<2;mi++)
    #pragma unroll
    for (int ni=0;ni<4;ni++) acc[mi][ni] = (f32x4){0.f,0.f,0.f,0.f};

  #pragma unroll
  for (int kc=0; kc<4; kc++){
    #pragma unroll
    for (int p=0; p<2; p++){
      const unsigned short* As = p ? A1s : A0s;
      const unsigned short* Wp = Wsp + (size_t)p*3*16384;
      s16x8 af[3][2], bf[3][4];
      #pragma unroll
      for (int mi=0; mi<2; mi++){
        int tile = (m0 + wm*32 + mi*16) >> 4;
        size_t idx = (size_t)tile*2048 + (size_t)(kc*4+lk)*128 + (size_t)lr*8;
        af[0][mi] = *(const s16x8*)&As[idx];
        af[1][mi] = *(const s16x8*)&As[PL + idx];
        af[2][mi] = *(const s16x8*)&As[2*PL + idx];
      }
      #pragma unroll
      for (int ni=0; ni<4; ni++){
        int ct = wn*4 + ni;
        size_t idx = (size_t)ct*2048 + (size_t)(kc*4+lk)*128 + (size_t)lr*8;
        bf[0][ni] = *(const s16x8*)&Wp[idx];
        bf[1][ni] = *(const s16x8*)&Wp[16384 + idx];
        bf[2][ni] = *(const s16x8*)&Wp[32768 + idx];
      }
      #define TRM(sa,sb) \
        _Pragma("unroll") \
        for (int ni=0; ni<4; ni++){ \
          _Pragma("unroll") \
          for (int mi=0; mi<2; mi++){ \
            acc[mi][ni] = __builtin_amdgcn_mfma_f32_16x16x32_bf16(af[sa][mi], bf[sb][ni], acc[mi][ni], 0,0,0); \
          } \
        }
      TRM(0,0) TRM(0,1) TRM(1,0) TRM(1,1) TRM(0,2) TRM(2,0)
      #undef TRM
    }
  }

  float nrm = *norm_p;
  float pwv[4], biasv[4];
  #pragma unroll
  for (int ni=0;ni<4;ni++){
    int col = wn*64 + ni*16 + lr;
    pwv[ni] = pw[col]; biasv[ni] = bias[col];
  }
  #pragma unroll
  for (int mi=0; mi<2; mi++){
    #pragma unroll
    for (int reg=0; reg<4; reg++){
      int rl = wm*32 + mi*16 + lk*4 + reg;
      int row = m0 + rl;
      float hv[4]; float sc = 0.f;
      #pragma unroll
      for (int ni=0; ni<4; ni++){
        hv[ni] = fmaxf(acc[mi][ni][reg] + biasv[ni], 0.f);
        sc += hv[ni]*pwv[ni];
      }
      if (row < M){
        #pragma unroll
        for (int ni=0; ni<4; ni++)
          hout[(size_t)row*Hc + wn*64 + ni*16 + lr] = hv[ni];
      }
      sc += __shfl_xor(sc,1); sc += __shfl_xor(sc,2);
      sc += __shfl_xor(sc,4); sc += __shfl_xor(sc,8);
      if (lr == 0) scds[rl][wn] = sc;
    }
  }
  __syncthreads();
  if (tid < 64){
    int row = m0 + tid;
    if (row < M) score[row] = tanhf((scds[tid][0] + scds[tid][1]) / nrm);
  }
}

// ---------------- MLP head ---------------------------------------------------
__launch_bounds__(512)
__global__ void k_mlp(const float* __restrict__ z,
                      const float* __restrict__ Wl1T, const float* __restrict__ bl1,
                      const float* __restrict__ Wl2T, const float* __restrict__ bl2,
                      const float* __restrict__ Wl3, const float* __restrict__ bl3,
                      float* __restrict__ out){
  __shared__ float zs[256];
  __shared__ float u1[512];
  int g = blockIdx.x, t = threadIdx.x;
  if (t < 256) zs[t] = z[g*256 + t];
  __syncthreads();
  {
    float acc = bl1[t];
    #pragma unroll 8
    for (int f=0; f<256; f++) acc = fmaf(zs[f], Wl1T[f*512 + t], acc);
    u1[t] = fmaxf(acc, 0.f);
  }
  __syncthreads();
  if (t < 64){
    float acc = bl2[t];
    #pragma unroll 8
    for (int f=0; f<512; f++) acc = fmaf(u1[f], Wl2T[f*64 + t], acc);
    float v = fmaxf(acc, 0.f) * Wl3[t];
    for (int o=32;o>0;o>>=1) v += __shfl_xor(v, o);
    if (t == 0) out[g] = v + bl3[0];
  }
}

extern "C" void kernel_launch(void* const* d_in, const int* in_sizes, int n_in,
                              void* d_out, int out_size, void* d_ws, size_t ws_size,
                              hipStream_t stream){
  const float* x     = (const float*)d_in[0];
  const int*   esrc  = (const int*)d_in[1];
  const int*   edst  = (const int*)d_in[2];
  const float* Wrel1 = (const float*)d_in[5];
  const float* Wroot1= (const float*)d_in[6];
  const float* b1    = (const float*)d_in[7];
  const float* pw1   = (const float*)d_in[8];
  const float* Wrel2 = (const float*)d_in[9];
  const float* Wroot2= (const float*)d_in[10];
  const float* b2    = (const float*)d_in[11];
  const float* pw2   = (const float*)d_in[12];
  const float* Wrel3 = (const float*)d_in[13];
  const float* Wroot3= (const float*)d_in[14];
  const float* b3    = (const float*)d_in[15];
  const float* pw3   = (const float*)d_in[16];
  const float* Wl1   = (const float*)d_in[17];
  const float* bl1   = (const float*)d_in[18];
  const float* Wl2   = (const float*)d_in[19];
  const float* bl2   = (const float*)d_in[20];
  const float* Wl3   = (const float*)d_in[21];
  const float* bl3   = (const float*)d_in[22];
  float* out = (float*)d_out;

  char* ws = (char*)d_ws;
  size_t off = 0;
  auto alloc = [&](size_t elems)->void*{
    void* p = ws + off;
    off += ((elems*4 + 255)/256)*256;
    return p;
  };
  int*   deg    = (int*)alloc(N0);
  int*   rowptr = (int*)alloc(N0);
  int*   csr    = (int*)alloc(NE);
  int*   map1   = (int*)alloc(N0);
  int*   newid2 = (int*)alloc(N1);
  int*   map2   = (int*)alloc(N0);
  int*   perm1  = (int*)alloc(N1);
  int*   perm2  = (int*)alloc(N2);
  int*   perm3  = (int*)alloc(N3);
  int*   orig3  = (int*)alloc(N2);
  float* score1 = (float*)alloc(N0);
  float* score2 = (float*)alloc(N1);
  float* score3 = (float*)alloc(N2);
  float* svg    = (float*)alloc(N1);
  float* xp     = (float*)alloc((size_t)N0*16);
  float* Wl1T   = (float*)alloc(256*512);
  float* Wl2T   = (float*)alloc(512*64);
  unsigned short* Wsp = (unsigned short*)alloc(98304);   // 196608 bf16
  unsigned short* W1S = (unsigned short*)alloc(6144);    // 12288 bf16
  float* norms  = (float*)alloc(3);
  float* bigA   = (float*)alloc((size_t)N0*Hc);      // h1, then aggS (3 planes)
  float* hB     = (float*)alloc((size_t)N1*Hc);      // h2 -> h3
  float* hpA    = (float*)alloc((size_t)N1*Hc);      // hp f32 row-major
  unsigned short* hpS = (unsigned short*)alloc((size_t)3*N1*Hc/2);  // 3 planes, frag layout
  float* z      = (float*)alloc(BG*256);

  float* h1   = bigA;
  unsigned short* aggS = (unsigned short*)bigA;   // h1 dead by then
  unsigned short* a1S  = hpS;                     // dead before gath fills hpS
  float* h2   = hB;
  float* h3   = hB;

  // front: CSR + weight prep + z zero + norms + x pack (one launch)
  k_front<<<3656, 512, 0, stream>>>(esrc, edst, x,
                                    Wrel1, Wroot1, Wrel2, Wroot2, Wrel3, Wroot3,
                                    Wl1, Wl2, pw1, pw2, pw3,
                                    deg, rowptr, csr, xp,
                                    Wl1T, Wl2T, Wsp, W1S, z, norms);

  // layer 1
  k_agg1s  <<<N0/4, 256, 0, stream>>>(xp, csr, rowptr, deg, a1S);
  k_conv1m <<<N0/64, 256, 0, stream>>>(a1S, W1S, b1, pw1, norms+0, h1, score1, N0);
  k_sortk<NPGc, K1c, 512><<<BG, 512, 0, stream>>>(score1, map1, perm1,
                                                  nullptr, nullptr, nullptr, nullptr, svg);
  k_gath   <<<BG, 1024, 0, stream>>>(h1, perm1, svg, hpA, hpS, z, K1c, 1);

  // layer 2
  k_aggHs  <<<N1/4, 256, 0, stream>>>(perm1, map1, hpA, csr, rowptr, deg, aggS, N1);
  k_convH  <<<N1/64, 256, 0, stream>>>(aggS, hpS, Wsp, b2, pw2, norms+1, h2, score2, N1);
  k_sortk<K1c, K2c, 256><<<BG, 256, 0, stream>>>(score2, newid2, perm2,
                                                 map1, map2, perm1, orig3, svg);
  k_gath   <<<BG, 1024, 0, stream>>>(h2, perm2, svg, hpA, hpS, z, K2c, 1);

  // layer 3  (grid padded to x8 for bijective XCD swizzle)
  k_aggHs  <<<10256, 256, 0, stream>>>(orig3, map2, hpA, csr, rowptr, deg, aggS, N2);
  k_convH  <<<(N2+63)/64, 256, 0, stream>>>(aggS, hpS, Wsp + 98304, b3, pw3, norms+2,
                                            h3, score3, N2);
  k_sortk<K2c, K3c, 256><<<BG, 256, 0, stream>>>(score3, newid2, perm3,
                                                 nullptr, nullptr, nullptr, nullptr, svg);
  k_gath   <<<BG, 1024, 0, stream>>>(h3, perm3, svg, nullptr, hpS, z, K3c, 0);

  // head
  k_mlp<<<BG, 512, 0, stream>>>(z, Wl1T, bl1, Wl2T, bl2, Wl3, bl3, out);
}

// Round 20
// 276.217 us; speedup vs baseline: 1.0278x; 1.0278x over previous
//
#include <hip/hip_runtime.h>
#include <math.h>

#define BG   200
#define NPGc 512
#define EPGc 8192
#define NE   (BG*EPGc)     // 1638400
#define N0   (BG*NPGc)     // 102400
#define FINc 11
#define Hc   128
#define K1c  256
#define K2c  205
#define K3c  164
#define N1   (BG*K1c)      // 51200
#define N2   (BG*K2c)      // 41000
#define N3   (BG*K3c)      // 32800

typedef float f32x4 __attribute__((ext_vector_type(4)));
typedef short s16x8 __attribute__((ext_vector_type(8)));

#define PL ((size_t)N1*Hc)      // hpS/aggS plane stride (elements)
#define PA ((size_t)N0*32)      // conv1 A-plane stride (elements)

// ---- 3-way RNE bf16 split: v = p0 + p1 + p2 + O(2^-24 |v|) -----------------
__device__ inline unsigned short bf16_rne(float v){
  unsigned u = __float_as_uint(v);
  unsigned r = u + 0x7FFFu + ((u >> 16) & 1u);
  return (unsigned short)(r >> 16);
}
__device__ inline float bf16_f32(unsigned short h){
  return __uint_as_float(((unsigned)h) << 16);
}
__device__ inline void split3(float v, unsigned short& r0, unsigned short& r1,
                              unsigned short& r2){
  r0 = bf16_rne(v); float v1 = v - bf16_f32(r0);
  r1 = bf16_rne(v1); float v2 = v1 - bf16_f32(r1);
  r2 = bf16_rne(v2);
}

// fragment-native layout, K=128: (row,k) -> [row>>4][k>>3][row&15][k&7]
__device__ inline size_t flIdx(int row, int k){
  return ((size_t)(row >> 4))*2048 + (size_t)(k >> 3)*128
       + (size_t)(row & 15)*8 + (size_t)(k & 7);
}
// same, K=32 (tile = 512 elems)
__device__ inline size_t flIdx32(int row, int k){
  return ((size_t)(row >> 4))*512 + (size_t)(k >> 3)*128
       + (size_t)(row & 15)*8 + (size_t)(k & 7);
}

// ---------------- front kernel: CSR build + weight prep + x pack -------------
__launch_bounds__(512)
__global__ void k_front(const int* __restrict__ esrc, const int* __restrict__ edst,
                        const float* __restrict__ x,
                        const float* __restrict__ Wrel1, const float* __restrict__ Wroot1,
                        const float* __restrict__ Wrel2, const float* __restrict__ Wroot2,
                        const float* __restrict__ Wrel3, const float* __restrict__ Wroot3,
                        const float* __restrict__ Wl1, const float* __restrict__ Wl2,
                        const float* __restrict__ pw1, const float* __restrict__ pw2,
                        const float* __restrict__ pw3,
                        int* __restrict__ deg, int* __restrict__ rowptr,
                        int* __restrict__ csr, float* __restrict__ xp,
                        float* __restrict__ Wl1T, float* __restrict__ Wl2T,
                        unsigned short* __restrict__ Wsp, unsigned short* __restrict__ W1S,
                        float* __restrict__ z, float* __restrict__ norms){
  int b = blockIdx.x, t = threadIdx.x;
  if (b < BG){
    __shared__ int ed[EPGc];    // 32 KB
    __shared__ int cnt[NPGc];
    __shared__ int sc[NPGc];
    int g = b;
    cnt[t] = 0;
    __syncthreads();
    int gb = g*EPGc;
    for (int i=t; i<EPGc; i+=512){
      int dl = edst[gb+i] & (NPGc-1);
      ed[i] = dl;
      atomicAdd(&cnt[dl], 1);
    }
    __syncthreads();
    int d = cnt[t];
    sc[t] = d;
    __syncthreads();
    for (int o=1;o<NPGc;o<<=1){
      int v = (t>=o) ? sc[t-o] : 0;
      __syncthreads();
      sc[t] += v;
      __syncthreads();
    }
    deg[g*NPGc+t]    = d;
    rowptr[g*NPGc+t] = gb + sc[t] - d;
    cnt[t] = sc[t] - d;
    __syncthreads();
    for (int i=t; i<EPGc; i+=512){
      int p = atomicAdd(&cnt[ed[i]], 1);
      csr[gb+p] = esrc[gb+i];
    }
  } else if (b < 456){
    int idx = (b-200)*512 + t;     // 0..131071
    if (idx < 256*512){
      int f = idx >> 9, tt = idx & 511;
      Wl1T[idx] = Wl1[tt*256 + f];
    }
    if (idx < 512*64){
      int f = idx >> 6, tt = idx & 63;
      Wl2T[idx] = Wl2[tt*512 + f];
    }
    if (idx < 65536){
      int L = idx >> 15, p = (idx >> 14) & 1, ck = idx & 16383;
      int c = ck >> 7, k = ck & 127;
      const float* W = L ? (p ? Wroot3 : Wrel3) : (p ? Wroot2 : Wrel2);
      unsigned short r0, r1, r2;
      split3(W[c*128 + k], r0, r1, r2);
      unsigned short* base = Wsp + (size_t)((L*2+p)*3)*16384;
      size_t fl = flIdx(c, k);
      base[fl]          = r0;
      base[16384 + fl]  = r1;
      base[32768 + fl]  = r2;
    }
    if (idx < 4096){
      int c = idx >> 5, k = idx & 31;
      float v = (k < 11) ? Wrel1[c*11 + k] : (k < 22 ? Wroot1[c*11 + (k-11)] : 0.f);
      unsigned short r0, r1, r2;
      split3(v, r0, r1, r2);
      size_t fl = flIdx32(c, k);
      W1S[fl]        = r0;
      W1S[4096 + fl] = r1;
      W1S[8192 + fl] = r2;
    }
    if (idx < BG*256) z[idx] = 0.f;
    if (b == 455){
      int w = t >> 6, lane = t & 63;
      if (w < 3){
        const float* pw = (w==0) ? pw1 : (w==1 ? pw2 : pw3);
        float v0 = pw[lane], v1 = pw[64+lane];
        float ss = v0*v0 + v1*v1;
        for (int o=32;o>0;o>>=1) ss += __shfl_xor(ss, o);
        if (lane == 0) norms[w] = sqrtf(ss);
      }
    }
  } else {
    int idx = (b-456)*512 + t;     // 0..N0*16-1
    int n = idx >> 4, f = idx & 15;
    xp[idx] = (f < FINc) ? x[n*FINc + f] : 0.f;
  }
}

// ---------------- layer 1: wave per dst, deep load batches, fused split ------
__launch_bounds__(256, 8)
__global__ void k_agg1s(const float* __restrict__ xp, const int* __restrict__ csr,
                        const int* __restrict__ rowptr, const int* __restrict__ deg,
                        unsigned short* __restrict__ AS){
  int bid = (int)((blockIdx.x & 7)*3200 + (blockIdx.x >> 3));
  int d = bid*4 + (threadIdx.x >> 6);
  if (d >= N0) return;
  int lane = threadIdx.x & 63;
  int slot = lane >> 4, f = lane & 15;
  int rs = rowptr[d], dg = deg[d];
  float a0 = 0.f, a1 = 0.f, a2 = 0.f, a3 = 0.f;
  for (int base=0; base<dg; base+=64){
    int e = base + lane;
    int s = 0;
    if (e < dg) s = csr[rs+e];
    int cnt = min(64, dg-base);
    int sv[16];
    #pragma unroll
    for (int u=0; u<16; u++) sv[u] = __shfl(s, u*4 + slot);
    #pragma unroll
    for (int u=0; u<16; u++){
      int ei = u*4 + slot;
      float v = 0.f;
      if (ei < cnt) v = xp[(sv[u] << 4) + f];
      if      ((u & 3) == 0) a0 += v;
      else if ((u & 3) == 1) a1 += v;
      else if ((u & 3) == 2) a2 += v;
      else                   a3 += v;
    }
  }
  a0 = (a0 + a1) + (a2 + a3);
  a0 += __shfl_xor(a0, 16);
  a0 += __shfl_xor(a0, 32);            // all lanes hold agg[f], f = lane&15
  int k0 = 2*lane, k1 = k0 + 1;
  float s0 = __shfl(a0, k0 & 15);
  float s1 = __shfl(a0, k1 & 15);
  if (lane < 16){
    float v0 = (k0 < 11) ? s0 : ((k0 < 22) ? xp[(d<<4) + k0 - 11] : 0.f);
    float v1 = (k1 < 11) ? s1 : ((k1 < 22) ? xp[(d<<4) + k1 - 11] : 0.f);
    unsigned short a_0,a_1,a_2,b_0,b_1,b_2;
    split3(v0, a_0, a_1, a_2);
    split3(v1, b_0, b_1, b_2);
    size_t fl = flIdx32(d, k0);
    *(unsigned*)&AS[fl]        = (unsigned)a_0 | ((unsigned)b_0 << 16);
    *(unsigned*)&AS[PA + fl]   = (unsigned)a_1 | ((unsigned)b_1 << 16);
    *(unsigned*)&AS[2*PA + fl] = (unsigned)a_2 | ((unsigned)b_2 << 16);
  }
}

// ---------------- conv1: 6-term split MFMA, K=32, fused score ---------------
__launch_bounds__(256)
__global__ void k_conv1m(const unsigned short* __restrict__ AS,
                         const unsigned short* __restrict__ W1S,
                         const float* __restrict__ bias, const float* __restrict__ pw,
                         const float* __restrict__ norm_p,
                         float* __restrict__ hout, float* __restrict__ score, int M){
  __shared__ float scds[64][2];
  int tid = threadIdx.x;
  int w = tid >> 6, l = tid & 63;
  int wm = w >> 1, wn = w & 1;
  int lr = l & 15, lk = l >> 4;
  int m0 = blockIdx.x * 64;

  f32x4 acc[2][4];
  #pragma unroll
  for (int mi=0;mi<2;mi++)
    #pragma unroll
    for (int ni=0;ni<4;ni++) acc[mi][ni] = (f32x4){0.f,0.f,0.f,0.f};

  s16x8 af[3][2], bf[3][4];
  #pragma unroll
  for (int mi=0; mi<2; mi++){
    int tile = (m0 + wm*32 + mi*16) >> 4;
    size_t idx = (size_t)tile*512 + (size_t)lk*128 + (size_t)lr*8;
    af[0][mi] = *(const s16x8*)&AS[idx];
    af[1][mi] = *(const s16x8*)&AS[PA + idx];
    af[2][mi] = *(const s16x8*)&AS[2*PA + idx];
  }
  #pragma unroll
  for (int ni=0; ni<4; ni++){
    int ct = wn*4 + ni;
    size_t idx = (size_t)ct*512 + (size_t)lk*128 + (size_t)lr*8;
    bf[0][ni] = *(const s16x8*)&W1S[idx];
    bf[1][ni] = *(const s16x8*)&W1S[4096 + idx];
    bf[2][ni] = *(const s16x8*)&W1S[8192 + idx];
  }
  #define TRM(sa,sb) \
    _Pragma("unroll") \
    for (int ni=0; ni<4; ni++){ \
      _Pragma("unroll") \
      for (int mi=0; mi<2; mi++){ \
        acc[mi][ni] = __builtin_amdgcn_mfma_f32_16x16x32_bf16(af[sa][mi], bf[sb][ni], acc[mi][ni], 0,0,0); \
      } \
    }
  TRM(0,0) TRM(0,1) TRM(1,0) TRM(1,1) TRM(0,2) TRM(2,0)
  #undef TRM

  float nrm = *norm_p;
  float pwv[4], biasv[4];
  #pragma unroll
  for (int ni=0;ni<4;ni++){
    int col = wn*64 + ni*16 + lr;
    pwv[ni] = pw[col]; biasv[ni] = bias[col];
  }
  #pragma unroll
  for (int mi=0; mi<2; mi++){
    #pragma unroll
    for (int reg=0; reg<4; reg++){
      int rl = wm*32 + mi*16 + lk*4 + reg;
      int row = m0 + rl;
      float hv[4]; float sc = 0.f;
      #pragma unroll
      for (int ni=0; ni<4; ni++){
        hv[ni] = fmaxf(acc[mi][ni][reg] + biasv[ni], 0.f);
        sc += hv[ni]*pwv[ni];
      }
      if (row < M){
        #pragma unroll
        for (int ni=0; ni<4; ni++)
          hout[(size_t)row*Hc + wn*64 + ni*16 + lr] = hv[ni];
      }
      sc += __shfl_xor(sc,1); sc += __shfl_xor(sc,2);
      sc += __shfl_xor(sc,4); sc += __shfl_xor(sc,8);
      if (lr == 0) scds[rl][wn] = sc;
    }
  }
  __syncthreads();
  if (tid < 64){
    int row = m0 + tid;
    if (row < M) score[row] = tanhf((scds[tid][0] + scds[tid][1]) / nrm);
  }
}

// ---------------- fused topk + compose + gather + split + readout (+MLP) -----
template<int N, int K, int NP2, bool DOSPLIT, bool DOMLP>
__launch_bounds__(1024)
__global__ void k_topg(const float* __restrict__ score, const float* __restrict__ h,
                       int* __restrict__ newid, int* __restrict__ perm,
                       const int* __restrict__ map1In, int* __restrict__ map2Out,
                       const int* __restrict__ origPrev, int* __restrict__ origOut,
                       float* __restrict__ hp, unsigned short* __restrict__ hpS,
                       float* __restrict__ z,
                       const float* __restrict__ Wl1T, const float* __restrict__ bl1,
                       const float* __restrict__ Wl2T, const float* __restrict__ bl2,
                       const float* __restrict__ Wl3, const float* __restrict__ bl3,
                       float* __restrict__ out){
  __shared__ float sv[NP2];
  __shared__ int   si[NP2];
  __shared__ int   nid[N];
  __shared__ float2 smx2[16][64];
  __shared__ float2 ssm2[16][64];
  __shared__ float zfin[256];
  __shared__ float u1[512];
  int g = blockIdx.x, t = threadIdx.x;

  float v = -INFINITY; int ix = t;
  if (t < NP2 && t < N) v = score[g*N + t];

  for (int k=2;k<=NP2;k<<=1){
    for (int j=k>>1;j>0;j>>=1){
      if (j >= 64){
        if (t < NP2){ sv[t] = v; si[t] = ix; }
        __syncthreads();
        if (t < NP2){
          int p = t ^ j;
          float vp = sv[p]; int ip = si[p];
          bool pre = (v > vp) || (v == vp && ix < ip);
          bool up = ((t & k) == 0);
          bool lower = ((t & j) == 0);
          bool keep = lower ? (pre == up) : (pre != up);
          if (!keep){ v = vp; ix = ip; }
        }
        __syncthreads();
      } else {
        if (t < NP2){
          float vp = __shfl_xor(v, j);
          int   ip = __shfl_xor(ix, j);
          bool pre = (v > vp) || (v == vp && ix < ip);
          bool up = ((t & k) == 0);
          bool lower = ((t & j) == 0);
          bool keep = lower ? (pre == up) : (pre != up);
          if (!keep){ v = vp; ix = ip; }
        }
      }
    }
  }
  if (t < NP2){ sv[t] = v; si[t] = ix; }
  __syncthreads();

  if (t < N) nid[si[t]] = (t < K) ? t : -1;
  __syncthreads();
  if (t < N) newid[g*N + t] = (nid[t] >= 0) ? g*K + nid[t] : -1;
  if (t < K){
    int old = si[t];
    perm[g*K + t] = g*N + old;
    if (origOut) origOut[g*K + t] = origPrev[g*N + old];
  }
  if (map2Out){
    for (int o = t; o < NPGc; o += 1024){
      int m = map1In[g*NPGc + o];
      int r = (m >= 0) ? nid[m - g*N] : -1;
      map2Out[g*NPGc + o] = (r >= 0) ? g*K + r : -1;
    }
  }
  __syncthreads();

  // gather: 16 row-groups x 64 col-pairs; all NB loads in flight first.
  constexpr int NB = (K + 15) / 16;
  int rg = t >> 6, j2 = t & 63;
  float2 vv[NB];
  #pragma unroll
  for (int i=0; i<NB; i++){
    int r = rg + 16*i;
    float2 val = make_float2(0.f, 0.f);
    if (r < K){
      int old = si[r];
      val = *(const float2*)&h[(size_t)(g*N + old)*Hc + 2*j2];
      float sc = sv[r];
      val.x *= sc; val.y *= sc;
    }
    vv[i] = val;
  }
  float mx = -INFINITY, my = -INFINITY, sx = 0.f, sy = 0.f;
  #pragma unroll
  for (int i=0; i<NB; i++){
    int r = rg + 16*i;
    if (r < K){
      int m = g*K + r;
      if (hp) *(float2*)&hp[(size_t)m*Hc + 2*j2] = vv[i];
      if constexpr (DOSPLIT){
        unsigned short a0,a1,a2,b0,b1,b2;
        split3(vv[i].x, a0, a1, a2);
        split3(vv[i].y, b0, b1, b2);
        size_t fl = flIdx(m, 2*j2);
        *(unsigned*)&hpS[fl]        = (unsigned)a0 | ((unsigned)b0 << 16);
        *(unsigned*)&hpS[PL + fl]   = (unsigned)a1 | ((unsigned)b1 << 16);
        *(unsigned*)&hpS[2*PL + fl] = (unsigned)a2 | ((unsigned)b2 << 16);
      }
      mx = fmaxf(mx, vv[i].x); my = fmaxf(my, vv[i].y);
      sx += vv[i].x; sy += vv[i].y;
    }
  }
  smx2[rg][j2] = make_float2(mx, my);
  ssm2[rg][j2] = make_float2(sx, sy);
  __syncthreads();
  if (t < 64){
    float2 M = smx2[0][t], S = ssm2[0][t];
    #pragma unroll
    for (int u=1; u<16; u++){
      float2 m2 = smx2[u][t], s2 = ssm2[u][t];
      M.x = fmaxf(M.x, m2.x); M.y = fmaxf(M.y, m2.y);
      S.x += s2.x; S.y += s2.y;
    }
    int c0 = 2*t, c1 = 2*t + 1;
    if constexpr (DOMLP){
      zfin[c0]       = z[g*256 + c0]       + M.x;
      zfin[c1]       = z[g*256 + c1]       + M.y;
      zfin[128 + c0] = z[g*256 + 128 + c0] + S.x / (float)K;
      zfin[128 + c1] = z[g*256 + 128 + c1] + S.y / (float)K;
    } else {
      z[g*256 + c0]       += M.x;
      z[g*256 + c1]       += M.y;
      z[g*256 + 128 + c0] += S.x / (float)K;
      z[g*256 + 128 + c1] += S.y / (float)K;
    }
  }
  if constexpr (DOMLP){
    __syncthreads();
    if (t < 512){
      float acc = bl1[t];
      #pragma unroll 8
      for (int f=0; f<256; f++) acc = fmaf(zfin[f], Wl1T[f*512 + t], acc);
      u1[t] = fmaxf(acc, 0.f);
    }
    __syncthreads();
    if (t < 64){
      float acc = bl2[t];
      #pragma unroll 8
      for (int f=0; f<512; f++) acc = fmaf(u1[f], Wl2T[f*64 + t], acc);
      float vy = fmaxf(acc, 0.f) * Wl3[t];
      for (int o=32;o>0;o>>=1) vy += __shfl_xor(vy, o);
      if (t == 0) out[g] = vy + bl3[0];
    }
  }
}

// ---------------- layers 2/3 aggregation: compact list, 8 chains -------------
__launch_bounds__(256, 4)
__global__ void k_aggHs(const int* __restrict__ orig, const int* __restrict__ map,
                        const float* __restrict__ hp,
                        const int* __restrict__ csr, const int* __restrict__ rowptr,
                        const int* __restrict__ deg, unsigned short* __restrict__ aggS,
                        int M){
  int cpx = gridDim.x >> 3;
  int bid = (int)((blockIdx.x & 7)*cpx + (blockIdx.x >> 3));
  int m = bid*4 + (threadIdx.x>>6);
  int lane = threadIdx.x & 63;
  if (m >= M) return;
  int d = orig[m];
  int rs = rowptr[d], dg = deg[d];
  int half = lane >> 5, cl = lane & 31;
  f32x4 acc[8];
  #pragma unroll
  for (int u=0;u<8;u++) acc[u] = (f32x4){0.f,0.f,0.f,0.f};
  for (int base=0; base<dg; base+=64){
    int e = base + lane;
    int ns = -1;
    if (e < dg){ int s = csr[rs+e]; ns = map[s]; }
    int cnt = min(64, dg-base);
    for (int jj=0; jj<cnt; jj+=16){
      #pragma unroll
      for (int u=0; u<8; u++){
        int ei = jj + u*2 + half;
        int nsj = __shfl(ns, ei & 63);
        if (ei < cnt && nsj >= 0){
          acc[u] += *(const f32x4*)(hp + (size_t)nsj*Hc + cl*4);
        }
      }
    }
  }
  f32x4 s4 = ((acc[0]+acc[1]) + (acc[2]+acc[3])) + ((acc[4]+acc[5]) + (acc[6]+acc[7]));
  #pragma unroll
  for (int i=0;i<4;i++) s4[i] += __shfl_xor(s4[i], 32);
  float e0 = __shfl(s4[0], lane>>1);
  float e1 = __shfl(s4[1], lane>>1);
  float e2 = __shfl(s4[2], lane>>1);
  float e3 = __shfl(s4[3], lane>>1);
  float cx = (lane&1) ? e2 : e0;
  float cy = (lane&1) ? e3 : e1;
  unsigned short x0,x1,x2,y0,y1,y2;
  split3(cx, x0, x1, x2);
  split3(cy, y0, y1, y2);
  size_t fl = flIdx(m, 2*lane);
  *(unsigned*)&aggS[fl]        = (unsigned)x0 | ((unsigned)y0 << 16);
  *(unsigned*)&aggS[PL + fl]   = (unsigned)x1 | ((unsigned)y1 << 16);
  *(unsigned*)&aggS[2*PL + fl] = (unsigned)x2 | ((unsigned)y2 << 16);
}

// ---------------- conv2/conv3: 6-term split MFMA, fused score ----------------
__launch_bounds__(256)
__global__ void k_convH(const unsigned short* __restrict__ A0s,
                        const unsigned short* __restrict__ A1s,
                        const unsigned short* __restrict__ Wsp,
                        const float* __restrict__ bias, const float* __restrict__ pw,
                        const float* __restrict__ norm_p,
                        float* __restrict__ hout, float* __restrict__ score, int M){
  __shared__ float scds[64][2];
  int tid = threadIdx.x;
  int w = tid >> 6, l = tid & 63;
  int wm = w >> 1, wn = w & 1;
  int lr = l & 15, lk = l >> 4;
  int m0 = blockIdx.x * 64;

  f32x4 acc[2][4];
  #pragma unroll
  for (int mi=0;mi<2;mi++)
    #pragma unroll
    for (int ni=0;ni<4;ni++) acc[mi][ni] = (f32x4){0.f,0.f,0.f,0.f};

  #pragma unroll
  for (int kc=0; kc<4; kc++){
    #pragma unroll
    for (int p=0; p<2; p++){
      const unsigned short* As = p ? A1s : A0s;
      const unsigned short* Wp = Wsp + (size_t)p*3*16384;
      s16x8 af[3][2], bf[3][4];
      #pragma unroll
      for (int mi=0; mi<2; mi++){
        int tile = (m0 + wm*32 + mi*16) >> 4;
        size_t idx = (size_t)tile*2048 + (size_t)(kc*4+lk)*128 + (size_t)lr*8;
        af[0][mi] = *(const s16x8*)&As[idx];
        af[1][mi] = *(const s16x8*)&As[PL + idx];
        af[2][mi] = *(const s16x8*)&As[2*PL + idx];
      }
      #pragma unroll
      for (int ni=0; ni<4; ni++){
        int ct = wn*4 + ni;
        size_t idx = (size_t)ct*2048 + (size_t)(kc*4+lk)*128 + (size_t)lr*8;
        bf[0][ni] = *(const s16x8*)&Wp[idx];
        bf[1][ni] = *(const s16x8*)&Wp[16384 + idx];
        bf[2][ni] = *(const s16x8*)&Wp[32768 + idx];
      }
      #define TRM(sa,sb) \
        _Pragma("unroll") \
        for (int ni=0; ni<4; ni++){ \
          _Pragma("unroll") \
          for (int mi=0; mi<2; mi++){ \
            acc[mi][ni] = __builtin_amdgcn_mfma_f32_16x16x32_bf16(af[sa][mi], bf[sb][ni], acc[mi][ni], 0,0,0); \
          } \
        }
      TRM(0,0) TRM(0,1) TRM(1,0) TRM(1,1) TRM(0,2) TRM(2,0)
      #undef TRM
    }
  }

  float nrm = *norm_p;
  float pwv[4], biasv[4];
  #pragma unroll
  for (int ni=0;ni<4;ni++){
    int col = wn*64 + ni*16 + lr;
    pwv[ni] = pw[col]; biasv[ni] = bias[col];
  }
  #pragma unroll
  for (int mi=0; mi<2; mi++){
    #pragma unroll
    for (int reg=0; reg<4; reg++){
      int rl = wm*32 + mi*16 + lk*4 + reg;
      int row = m0 + rl;
      float hv[4]; float sc = 0.f;
      #pragma unroll
      for (int ni=0; ni<4; ni++){
        hv[ni] = fmaxf(acc[mi][ni][reg] + biasv[ni], 0.f);
        sc += hv[ni]*pwv[ni];
      }
      if (row < M){
        #pragma unroll
        for (int ni=0; ni<4; ni++)
          hout[(size_t)row*Hc + wn*64 + ni*16 + lr] = hv[ni];
      }
      sc += __shfl_xor(sc,1); sc += __shfl_xor(sc,2);
      sc += __shfl_xor(sc,4); sc += __shfl_xor(sc,8);
      if (lr == 0) scds[rl][wn] = sc;
    }
  }
  __syncthreads();
  if (tid < 64){
    int row = m0 + tid;
    if (row < M) score[row] = tanhf((scds[tid][0] + scds[tid][1]) / nrm);
  }
}

extern "C" void kernel_launch(void* const* d_in, const int* in_sizes, int n_in,
                              void* d_out, int out_size, void* d_ws, size_t ws_size,
                              hipStream_t stream){
  const float* x     = (const float*)d_in[0];
  const int*   esrc  = (const int*)d_in[1];
  const int*   edst  = (const int*)d_in[2];
  const float* Wrel1 = (const float*)d_in[5];
  const float* Wroot1= (const float*)d_in[6];
  const float* b1    = (const float*)d_in[7];
  const float* pw1   = (const float*)d_in[8];
  const float* Wrel2 = (const float*)d_in[9];
  const float* Wroot2= (const float*)d_in[10];
  const float* b2    = (const float*)d_in[11];
  const float* pw2   = (const float*)d_in[12];
  const float* Wrel3 = (const float*)d_in[13];
  const float* Wroot3= (const float*)d_in[14];
  const float* b3    = (const float*)d_in[15];
  const float* pw3   = (const float*)d_in[16];
  const float* Wl1   = (const float*)d_in[17];
  const float* bl1   = (const float*)d_in[18];
  const float* Wl2   = (const float*)d_in[19];
  const float* bl2   = (const float*)d_in[20];
  const float* Wl3   = (const float*)d_in[21];
  const float* bl3   = (const float*)d_in[22];
  float* out = (float*)d_out;

  char* ws = (char*)d_ws;
  size_t off = 0;
  auto alloc = [&](size_t elems)->void*{
    void* p = ws + off;
    off += ((elems*4 + 255)/256)*256;
    return p;
  };
  int*   deg    = (int*)alloc(N0);
  int*   rowptr = (int*)alloc(N0);
  int*   csr    = (int*)alloc(NE);
  int*   map1   = (int*)alloc(N0);
  int*   newid2 = (int*)alloc(N1);
  int*   map2   = (int*)alloc(N0);
  int*   perm1  = (int*)alloc(N1);
  int*   perm2  = (int*)alloc(N2);
  int*   perm3  = (int*)alloc(N3);
  int*   orig3  = (int*)alloc(N2);
  float* score1 = (float*)alloc(N0);
  float* score2 = (float*)alloc(N1);
  float* score3 = (float*)alloc(N2);
  float* xp     = (float*)alloc((size_t)N0*16);
  float* Wl1T   = (float*)alloc(256*512);
  float* Wl2T   = (float*)alloc(512*64);
  unsigned short* Wsp = (unsigned short*)alloc(98304);   // 196608 bf16
  unsigned short* W1S = (unsigned short*)alloc(6144);    // 12288 bf16
  float* norms  = (float*)alloc(3);
  float* bigA   = (float*)alloc((size_t)N0*Hc);      // h1, then aggS (3 planes)
  float* hB     = (float*)alloc((size_t)N1*Hc);      // h2 -> h3
  float* hpA    = (float*)alloc((size_t)N1*Hc);      // hp f32 row-major
  unsigned short* hpS = (unsigned short*)alloc((size_t)3*N1*Hc/2);  // 3 planes, frag layout
  float* z      = (float*)alloc(BG*256);

  float* h1   = bigA;
  unsigned short* aggS = (unsigned short*)bigA;   // h1 dead by then
  unsigned short* a1S  = hpS;                     // dead before topg fills hpS
  float* h2   = hB;
  float* h3   = hB;

  // front: CSR + weight prep + z zero + norms + x pack (one launch)
  k_front<<<3656, 512, 0, stream>>>(esrc, edst, x,
                                    Wrel1, Wroot1, Wrel2, Wroot2, Wrel3, Wroot3,
                                    Wl1, Wl2, pw1, pw2, pw3,
                                    deg, rowptr, csr, xp,
                                    Wl1T, Wl2T, Wsp, W1S, z, norms);

  // layer 1
  k_agg1s  <<<N0/4, 256, 0, stream>>>(xp, csr, rowptr, deg, a1S);
  k_conv1m <<<N0/64, 256, 0, stream>>>(a1S, W1S, b1, pw1, norms+0, h1, score1, N0);
  k_topg<NPGc, K1c, 512, true, false><<<BG, 1024, 0, stream>>>(
      score1, h1, map1, perm1, nullptr, nullptr, nullptr, nullptr,
      hpA, hpS, z, nullptr, nullptr, nullptr, nullptr, nullptr, nullptr, nullptr);

  // layer 2
  k_aggHs  <<<N1/4, 256, 0, stream>>>(perm1, map1, hpA, csr, rowptr, deg, aggS, N1);
  k_convH  <<<N1/64, 256, 0, stream>>>(aggS, hpS, Wsp, b2, pw2, norms+1, h2, score2, N1);
  k_topg<K1c, K2c, 256, true, false><<<BG, 1024, 0, stream>>>(
      score2, h2, newid2, perm2, map1, map2, perm1, orig3,
      hpA, hpS, z, nullptr, nullptr, nullptr, nullptr, nullptr, nullptr, nullptr);

  // layer 3  (grid padded to x8 for bijective XCD swizzle)
  k_aggHs  <<<10256, 256, 0, stream>>>(orig3, map2, hpA, csr, rowptr, deg, aggS, N2);
  k_convH  <<<(N2+63)/64, 256, 0, stream>>>(aggS, hpS, Wsp + 98304, b3, pw3, norms+2,
                                            h3, score3, N2);
  k_topg<K2c, K3c, 256, false, true><<<BG, 1024, 0, stream>>>(
      score3, h3, newid2, perm3, nullptr, nullptr, nullptr, nullptr,
      nullptr, nullptr, z, Wl1T, bl1, Wl2T, bl2, Wl3, bl3, out);
}

// Round 21
// 271.951 us; speedup vs baseline: 1.0440x; 1.0157x over previous
//
#include <hip/hip_runtime.h>
#include <math.h>

#define BG   200
#define NPGc 512
#define EPGc 8192
#define NE   (BG*EPGc)     // 1638400
#define N0   (BG*NPGc)     // 102400
#define FINc 11
#define Hc   128
#define K1c  256
#define K2c  205
#define K3c  164
#define N1   (BG*K1c)      // 51200
#define N2   (BG*K2c)      // 41000
#define N3   (BG*K3c)      // 32800

typedef float f32x4 __attribute__((ext_vector_type(4)));
typedef short s16x8 __attribute__((ext_vector_type(8)));

#define PL ((size_t)N1*Hc)      // hpS/aggS plane stride (elements)
#define PA ((size_t)N0*32)      // conv1 A-plane stride (elements)

// ---- 3-way RNE bf16 split: v = p0 + p1 + p2 + O(2^-24 |v|) -----------------
__device__ inline unsigned short bf16_rne(float v){
  unsigned u = __float_as_uint(v);
  unsigned r = u + 0x7FFFu + ((u >> 16) & 1u);
  return (unsigned short)(r >> 16);
}
__device__ inline float bf16_f32(unsigned short h){
  return __uint_as_float(((unsigned)h) << 16);
}
__device__ inline void split3(float v, unsigned short& r0, unsigned short& r1,
                              unsigned short& r2){
  r0 = bf16_rne(v); float v1 = v - bf16_f32(r0);
  r1 = bf16_rne(v1); float v2 = v1 - bf16_f32(r1);
  r2 = bf16_rne(v2);
}

// fragment-native layout, K=128: (row,k) -> [row>>4][k>>3][row&15][k&7]
__device__ inline size_t flIdx(int row, int k){
  return ((size_t)(row >> 4))*2048 + (size_t)(k >> 3)*128
       + (size_t)(row & 15)*8 + (size_t)(k & 7);
}
// same, K=32 (tile = 512 elems)
__device__ inline size_t flIdx32(int row, int k){
  return ((size_t)(row >> 4))*512 + (size_t)(k >> 3)*128
       + (size_t)(row & 15)*8 + (size_t)(k & 7);
}

// ---------------- front kernel: CSR build + weight prep + x pack -------------
__launch_bounds__(512)
__global__ void k_front(const int* __restrict__ esrc, const int* __restrict__ edst,
                        const float* __restrict__ x,
                        const float* __restrict__ Wrel1, const float* __restrict__ Wroot1,
                        const float* __restrict__ Wrel2, const float* __restrict__ Wroot2,
                        const float* __restrict__ Wrel3, const float* __restrict__ Wroot3,
                        const float* __restrict__ Wl1, const float* __restrict__ Wl2,
                        const float* __restrict__ pw1, const float* __restrict__ pw2,
                        const float* __restrict__ pw3,
                        int* __restrict__ deg, int* __restrict__ rowptr,
                        int* __restrict__ csr, float* __restrict__ xp,
                        float* __restrict__ Wl1T, float* __restrict__ Wl2T,
                        unsigned short* __restrict__ Wsp, unsigned short* __restrict__ W1S,
                        float* __restrict__ z, float* __restrict__ norms){
  int b = blockIdx.x, t = threadIdx.x;
  if (b < BG){
    __shared__ int ed[EPGc];    // 32 KB
    __shared__ int cnt[NPGc];
    __shared__ int sc[NPGc];
    int g = b;
    cnt[t] = 0;
    __syncthreads();
    int gb = g*EPGc;
    for (int i=t; i<EPGc; i+=512){
      int dl = edst[gb+i] & (NPGc-1);
      ed[i] = dl;
      atomicAdd(&cnt[dl], 1);
    }
    __syncthreads();
    int d = cnt[t];
    sc[t] = d;
    __syncthreads();
    for (int o=1;o<NPGc;o<<=1){
      int v = (t>=o) ? sc[t-o] : 0;
      __syncthreads();
      sc[t] += v;
      __syncthreads();
    }
    deg[g*NPGc+t]    = d;
    rowptr[g*NPGc+t] = gb + sc[t] - d;
    cnt[t] = sc[t] - d;
    __syncthreads();
    for (int i=t; i<EPGc; i+=512){
      int p = atomicAdd(&cnt[ed[i]], 1);
      csr[gb+p] = esrc[gb+i];
    }
  } else if (b < 456){
    int idx = (b-200)*512 + t;     // 0..131071
    if (idx < 256*512){
      int f = idx >> 9, tt = idx & 511;
      Wl1T[idx] = Wl1[tt*256 + f];
    }
    if (idx < 512*64){
      int f = idx >> 6, tt = idx & 63;
      Wl2T[idx] = Wl2[tt*512 + f];
    }
    if (idx < 65536){
      int L = idx >> 15, p = (idx >> 14) & 1, ck = idx & 16383;
      int c = ck >> 7, k = ck & 127;
      const float* W = L ? (p ? Wroot3 : Wrel3) : (p ? Wroot2 : Wrel2);
      unsigned short r0, r1, r2;
      split3(W[c*128 + k], r0, r1, r2);
      unsigned short* base = Wsp + (size_t)((L*2+p)*3)*16384;
      size_t fl = flIdx(c, k);
      base[fl]          = r0;
      base[16384 + fl]  = r1;
      base[32768 + fl]  = r2;
    }
    if (idx < 4096){
      int c = idx >> 5, k = idx & 31;
      float v = (k < 11) ? Wrel1[c*11 + k] : (k < 22 ? Wroot1[c*11 + (k-11)] : 0.f);
      unsigned short r0, r1, r2;
      split3(v, r0, r1, r2);
      size_t fl = flIdx32(c, k);
      W1S[fl]        = r0;
      W1S[4096 + fl] = r1;
      W1S[8192 + fl] = r2;
    }
    if (idx < BG*256) z[idx] = 0.f;
    if (b == 455){
      int w = t >> 6, lane = t & 63;
      if (w < 3){
        const float* pw = (w==0) ? pw1 : (w==1 ? pw2 : pw3);
        float v0 = pw[lane], v1 = pw[64+lane];
        float ss = v0*v0 + v1*v1;
        for (int o=32;o>0;o>>=1) ss += __shfl_xor(ss, o);
        if (lane == 0) norms[w] = sqrtf(ss);
      }
    }
  } else {
    int idx = (b-456)*512 + t;     // 0..N0*16-1
    int n = idx >> 4, f = idx & 15;
    xp[idx] = (f < FINc) ? x[n*FINc + f] : 0.f;
  }
}

// ---------------- layer 1: wave per dst, deep load batches, fused split ------
__launch_bounds__(256, 8)
__global__ void k_agg1s(const float* __restrict__ xp, const int* __restrict__ csr,
                        const int* __restrict__ rowptr, const int* __restrict__ deg,
                        unsigned short* __restrict__ AS){
  int bid = (int)((blockIdx.x & 7)*3200 + (blockIdx.x >> 3));
  int d = bid*4 + (threadIdx.x >> 6);
  if (d >= N0) return;
  int lane = threadIdx.x & 63;
  int slot = lane >> 4, f = lane & 15;
  int rs = rowptr[d], dg = deg[d];
  float a0 = 0.f, a1 = 0.f, a2 = 0.f, a3 = 0.f;
  for (int base=0; base<dg; base+=64){
    int e = base + lane;
    int s = 0;
    if (e < dg) s = csr[rs+e];
    int cnt = min(64, dg-base);
    int sv[16];
    #pragma unroll
    for (int u=0; u<16; u++) sv[u] = __shfl(s, u*4 + slot);
    #pragma unroll
    for (int u=0; u<16; u++){
      int ei = u*4 + slot;
      float v = 0.f;
      if (ei < cnt) v = xp[(sv[u] << 4) + f];
      if      ((u & 3) == 0) a0 += v;
      else if ((u & 3) == 1) a1 += v;
      else if ((u & 3) == 2) a2 += v;
      else                   a3 += v;
    }
  }
  a0 = (a0 + a1) + (a2 + a3);
  a0 += __shfl_xor(a0, 16);
  a0 += __shfl_xor(a0, 32);            // all lanes hold agg[f], f = lane&15
  int k0 = 2*lane, k1 = k0 + 1;
  float s0 = __shfl(a0, k0 & 15);
  float s1 = __shfl(a0, k1 & 15);
  if (lane < 16){
    float v0 = (k0 < 11) ? s0 : ((k0 < 22) ? xp[(d<<4) + k0 - 11] : 0.f);
    float v1 = (k1 < 11) ? s1 : ((k1 < 22) ? xp[(d<<4) + k1 - 11] : 0.f);
    unsigned short a_0,a_1,a_2,b_0,b_1,b_2;
    split3(v0, a_0, a_1, a_2);
    split3(v1, b_0, b_1, b_2);
    size_t fl = flIdx32(d, k0);
    *(unsigned*)&AS[fl]        = (unsigned)a_0 | ((unsigned)b_0 << 16);
    *(unsigned*)&AS[PA + fl]   = (unsigned)a_1 | ((unsigned)b_1 << 16);
    *(unsigned*)&AS[2*PA + fl] = (unsigned)a_2 | ((unsigned)b_2 << 16);
  }
}

// ---------------- conv1: 6-term split MFMA, K=32, fused score ---------------
__launch_bounds__(256)
__global__ void k_conv1m(const unsigned short* __restrict__ AS,
                         const unsigned short* __restrict__ W1S,
                         const float* __restrict__ bias, const float* __restrict__ pw,
                         const float* __restrict__ norm_p,
                         float* __restrict__ hout, float* __restrict__ score, int M){
  __shared__ float scds[64][2];
  int tid = threadIdx.x;
  int w = tid >> 6, l = tid & 63;
  int wm = w >> 1, wn = w & 1;
  int lr = l & 15, lk = l >> 4;
  int m0 = blockIdx.x * 64;

  f32x4 acc[2][4];
  #pragma unroll
  for (int mi=0;mi<2;mi++)
    #pragma unroll
    for (int ni=0;ni<4;ni++) acc[mi][ni] = (f32x4){0.f,0.f,0.f,0.f};

  s16x8 af[3][2], bf[3][4];
  #pragma unroll
  for (int mi=0; mi<2; mi++){
    int tile = (m0 + wm*32 + mi*16) >> 4;
    size_t idx = (size_t)tile*512 + (size_t)lk*128 + (size_t)lr*8;
    af[0][mi] = *(const s16x8*)&AS[idx];
    af[1][mi] = *(const s16x8*)&AS[PA + idx];
    af[2][mi] = *(const s16x8*)&AS[2*PA + idx];
  }
  #pragma unroll
  for (int ni=0; ni<4; ni++){
    int ct = wn*4 + ni;
    size_t idx = (size_t)ct*512 + (size_t)lk*128 + (size_t)lr*8;
    bf[0][ni] = *(const s16x8*)&W1S[idx];
    bf[1][ni] = *(const s16x8*)&W1S[4096 + idx];
    bf[2][ni] = *(const s16x8*)&W1S[8192 + idx];
  }
  #define TRM(sa,sb) \
    _Pragma("unroll") \
    for (int ni=0; ni<4; ni++){ \
      _Pragma("unroll") \
      for (int mi=0; mi<2; mi++){ \
        acc[mi][ni] = __builtin_amdgcn_mfma_f32_16x16x32_bf16(af[sa][mi], bf[sb][ni], acc[mi][ni], 0,0,0); \
      } \
    }
  TRM(0,0) TRM(0,1) TRM(1,0) TRM(1,1) TRM(0,2) TRM(2,0)
  #undef TRM

  float nrm = *norm_p;
  float pwv[4], biasv[4];
  #pragma unroll
  for (int ni=0;ni<4;ni++){
    int col = wn*64 + ni*16 + lr;
    pwv[ni] = pw[col]; biasv[ni] = bias[col];
  }
  #pragma unroll
  for (int mi=0; mi<2; mi++){
    #pragma unroll
    for (int reg=0; reg<4; reg++){
      int rl = wm*32 + mi*16 + lk*4 + reg;
      int row = m0 + rl;
      float hv[4]; float sc = 0.f;
      #pragma unroll
      for (int ni=0; ni<4; ni++){
        hv[ni] = fmaxf(acc[mi][ni][reg] + biasv[ni], 0.f);
        sc += hv[ni]*pwv[ni];
      }
      if (row < M){
        #pragma unroll
        for (int ni=0; ni<4; ni++)
          hout[(size_t)row*Hc + wn*64 + ni*16 + lr] = hv[ni];
      }
      sc += __shfl_xor(sc,1); sc += __shfl_xor(sc,2);
      sc += __shfl_xor(sc,4); sc += __shfl_xor(sc,8);
      if (lr == 0) scds[rl][wn] = sc;
    }
  }
  __syncthreads();
  if (tid < 64){
    int row = m0 + tid;
    if (row < M) score[row] = tanhf((scds[tid][0] + scds[tid][1]) / nrm);
  }
}

// ---------------- fused topk + compose + gather + split + readout (+MLP) -----
// Pass A: hp write (coalesced) + readout. Pass B: hpS fragment writes with
// octet thread mapping -> 16B-contiguous per thread, 256B per 16-lane cluster.
template<int N, int K, int NP2, bool DOSPLIT, bool DOMLP>
__launch_bounds__(1024)
__global__ void k_topg(const float* __restrict__ score, const float* __restrict__ h,
                       int* __restrict__ newid, int* __restrict__ perm,
                       const int* __restrict__ map1In, int* __restrict__ map2Out,
                       const int* __restrict__ origPrev, int* __restrict__ origOut,
                       float* __restrict__ hp, unsigned short* __restrict__ hpS,
                       float* __restrict__ z,
                       const float* __restrict__ Wl1T, const float* __restrict__ bl1,
                       const float* __restrict__ Wl2T, const float* __restrict__ bl2,
                       const float* __restrict__ Wl3, const float* __restrict__ bl3,
                       float* __restrict__ out){
  __shared__ float sv[NP2];
  __shared__ int   si[NP2];
  __shared__ int   nid[N];
  __shared__ float2 smx2[16][64];
  __shared__ float2 ssm2[16][64];
  __shared__ float zfin[256];
  __shared__ float u1[512];
  int g = blockIdx.x, t = threadIdx.x;

  float v = -INFINITY; int ix = t;
  if (t < NP2 && t < N) v = score[g*N + t];

  for (int k=2;k<=NP2;k<<=1){
    for (int j=k>>1;j>0;j>>=1){
      if (j >= 64){
        if (t < NP2){ sv[t] = v; si[t] = ix; }
        __syncthreads();
        if (t < NP2){
          int p = t ^ j;
          float vp = sv[p]; int ip = si[p];
          bool pre = (v > vp) || (v == vp && ix < ip);
          bool up = ((t & k) == 0);
          bool lower = ((t & j) == 0);
          bool keep = lower ? (pre == up) : (pre != up);
          if (!keep){ v = vp; ix = ip; }
        }
        __syncthreads();
      } else {
        if (t < NP2){
          float vp = __shfl_xor(v, j);
          int   ip = __shfl_xor(ix, j);
          bool pre = (v > vp) || (v == vp && ix < ip);
          bool up = ((t & k) == 0);
          bool lower = ((t & j) == 0);
          bool keep = lower ? (pre == up) : (pre != up);
          if (!keep){ v = vp; ix = ip; }
        }
      }
    }
  }
  if (t < NP2){ sv[t] = v; si[t] = ix; }
  __syncthreads();

  if (t < N) nid[si[t]] = (t < K) ? t : -1;
  __syncthreads();
  if (t < N) newid[g*N + t] = (nid[t] >= 0) ? g*K + nid[t] : -1;
  if (t < K){
    int old = si[t];
    perm[g*K + t] = g*N + old;
    if (origOut) origOut[g*K + t] = origPrev[g*N + old];
  }
  if (map2Out){
    for (int o = t; o < NPGc; o += 1024){
      int m = map1In[g*NPGc + o];
      int r = (m >= 0) ? nid[m - g*N] : -1;
      map2Out[g*NPGc + o] = (r >= 0) ? g*K + r : -1;
    }
  }
  __syncthreads();

  // ---- pass B (DOSPLIT): fragment-layout hpS writes, octet mapping ----
  // thread = (row rr = t&63, k-octet koct = t>>6); 16B store per plane.
  if constexpr (DOSPLIT){
    int rr = t & 63, koct = t >> 6;
    for (int r = rr; r < K; r += 64){
      int old = si[r];
      float sc = sv[r];
      int m = g*K + r;
      const float* src = &h[(size_t)(g*N + old)*Hc + koct*8];
      float4 f0 = *(const float4*)src;
      float4 f1 = *(const float4*)(src+4);
      float vals[8] = {f0.x,f0.y,f0.z,f0.w,f1.x,f1.y,f1.z,f1.w};
      s16x8 w0, w1, w2;
      #pragma unroll
      for (int i=0;i<8;i++){
        unsigned short p0,p1,p2;
        split3(vals[i]*sc, p0, p1, p2);
        w0[i] = (short)p0; w1[i] = (short)p1; w2[i] = (short)p2;
      }
      size_t fl = flIdx(m, koct*8);
      *(s16x8*)&hpS[fl]        = w0;
      *(s16x8*)&hpS[PL + fl]   = w1;
      *(s16x8*)&hpS[2*PL + fl] = w2;
    }
  }

  // ---- pass A: gather + hp write + readout ----
  constexpr int NB = (K + 15) / 16;
  int rg = t >> 6, j2 = t & 63;
  float2 vv[NB];
  #pragma unroll
  for (int i=0; i<NB; i++){
    int r = rg + 16*i;
    float2 val = make_float2(0.f, 0.f);
    if (r < K){
      int old = si[r];
      val = *(const float2*)&h[(size_t)(g*N + old)*Hc + 2*j2];
      float sc = sv[r];
      val.x *= sc; val.y *= sc;
    }
    vv[i] = val;
  }
  float mx = -INFINITY, my = -INFINITY, sx = 0.f, sy = 0.f;
  #pragma unroll
  for (int i=0; i<NB; i++){
    int r = rg + 16*i;
    if (r < K){
      int m = g*K + r;
      if (hp) *(float2*)&hp[(size_t)m*Hc + 2*j2] = vv[i];
      mx = fmaxf(mx, vv[i].x); my = fmaxf(my, vv[i].y);
      sx += vv[i].x; sy += vv[i].y;
    }
  }
  smx2[rg][j2] = make_float2(mx, my);
  ssm2[rg][j2] = make_float2(sx, sy);
  __syncthreads();
  if (t < 64){
    float2 M = smx2[0][t], S = ssm2[0][t];
    #pragma unroll
    for (int u=1; u<16; u++){
      float2 m2 = smx2[u][t], s2 = ssm2[u][t];
      M.x = fmaxf(M.x, m2.x); M.y = fmaxf(M.y, m2.y);
      S.x += s2.x; S.y += s2.y;
    }
    int c0 = 2*t, c1 = 2*t + 1;
    if constexpr (DOMLP){
      zfin[c0]       = z[g*256 + c0]       + M.x;
      zfin[c1]       = z[g*256 + c1]       + M.y;
      zfin[128 + c0] = z[g*256 + 128 + c0] + S.x / (float)K;
      zfin[128 + c1] = z[g*256 + 128 + c1] + S.y / (float)K;
    } else {
      z[g*256 + c0]       += M.x;
      z[g*256 + c1]       += M.y;
      z[g*256 + 128 + c0] += S.x / (float)K;
      z[g*256 + 128 + c1] += S.y / (float)K;
    }
  }
  if constexpr (DOMLP){
    __syncthreads();
    if (t < 512){
      float acc = bl1[t];
      #pragma unroll 8
      for (int f=0; f<256; f++) acc = fmaf(zfin[f], Wl1T[f*512 + t], acc);
      u1[t] = fmaxf(acc, 0.f);
    }
    __syncthreads();
    if (t < 64){
      float acc = bl2[t];
      #pragma unroll 8
      for (int f=0; f<512; f++) acc = fmaf(u1[f], Wl2T[f*64 + t], acc);
      float vy = fmaxf(acc, 0.f) * Wl3[t];
      for (int o=32;o>0;o>>=1) vy += __shfl_xor(vy, o);
      if (t == 0) out[g] = vy + bl3[0];
    }
  }
}

// ---------------- layers 2/3 aggregation: compact list, 8 chains -------------
__launch_bounds__(256, 4)
__global__ void k_aggHs(const int* __restrict__ orig, const int* __restrict__ map,
                        const float* __restrict__ hp,
                        const int* __restrict__ csr, const int* __restrict__ rowptr,
                        const int* __restrict__ deg, unsigned short* __restrict__ aggS,
                        int M){
  int cpx = gridDim.x >> 3;
  int bid = (int)((blockIdx.x & 7)*cpx + (blockIdx.x >> 3));
  int m = bid*4 + (threadIdx.x>>6);
  int lane = threadIdx.x & 63;
  if (m >= M) return;
  int d = orig[m];
  int rs = rowptr[d], dg = deg[d];
  int half = lane >> 5, cl = lane & 31;
  f32x4 acc[8];
  #pragma unroll
  for (int u=0;u<8;u++) acc[u] = (f32x4){0.f,0.f,0.f,0.f};
  for (int base=0; base<dg; base+=64){
    int e = base + lane;
    int ns = -1;
    if (e < dg){ int s = csr[rs+e]; ns = map[s]; }
    int cnt = min(64, dg-base);
    for (int jj=0; jj<cnt; jj+=16){
      #pragma unroll
      for (int u=0; u<8; u++){
        int ei = jj + u*2 + half;
        int nsj = __shfl(ns, ei & 63);
        if (ei < cnt && nsj >= 0){
          acc[u] += *(const f32x4*)(hp + (size_t)nsj*Hc + cl*4);
        }
      }
    }
  }
  f32x4 s4 = ((acc[0]+acc[1]) + (acc[2]+acc[3])) + ((acc[4]+acc[5]) + (acc[6]+acc[7]));
  #pragma unroll
  for (int i=0;i<4;i++) s4[i] += __shfl_xor(s4[i], 32);
  float e0 = __shfl(s4[0], lane>>1);
  float e1 = __shfl(s4[1], lane>>1);
  float e2 = __shfl(s4[2], lane>>1);
  float e3 = __shfl(s4[3], lane>>1);
  float cx = (lane&1) ? e2 : e0;
  float cy = (lane&1) ? e3 : e1;
  unsigned short x0,x1,x2,y0,y1,y2;
  split3(cx, x0, x1, x2);
  split3(cy, y0, y1, y2);
  size_t fl = flIdx(m, 2*lane);
  *(unsigned*)&aggS[fl]        = (unsigned)x0 | ((unsigned)y0 << 16);
  *(unsigned*)&aggS[PL + fl]   = (unsigned)x1 | ((unsigned)y1 << 16);
  *(unsigned*)&aggS[2*PL + fl] = (unsigned)x2 | ((unsigned)y2 << 16);
}

// ---------------- conv2/conv3: 6-term split MFMA, fused score ----------------
__launch_bounds__(256)
__global__ void k_convH(const unsigned short* __restrict__ A0s,
                        const unsigned short* __restrict__ A1s,
                        const unsigned short* __restrict__ Wsp,
                        const float* __restrict__ bias, const float* __restrict__ pw,
                        const float* __restrict__ norm_p,
                        float* __restrict__ hout, float* __restrict__ score, int M){
  __shared__ float scds[64][2];
  int tid = threadIdx.x;
  int w = tid >> 6, l = tid & 63;
  int wm = w >> 1, wn = w & 1;
  int lr = l & 15, lk = l >> 4;
  int m0 = blockIdx.x * 64;

  f32x4 acc[2][4];
  #pragma unroll
  for (int mi=0;mi<2;mi++)
    #pragma unroll
    for (int ni=0;ni<4;ni++) acc[mi][ni] = (f32x4){0.f,0.f,0.f,0.f};

  #pragma unroll
  for (int kc=0; kc<4; kc++){
    #pragma unroll
    for (int p=0; p<2; p++){
      const unsigned short* As = p ? A1s : A0s;
      const unsigned short* Wp = Wsp + (size_t)p*3*16384;
      s16x8 af[3][2], bf[3][4];
      #pragma unroll
      for (int mi=0; mi<2; mi++){
        int tile = (m0 + wm*32 + mi*16) >> 4;
        size_t idx = (size_t)tile*2048 + (size_t)(kc*4+lk)*128 + (size_t)lr*8;
        af[0][mi] = *(const s16x8*)&As[idx];
        af[1][mi] = *(const s16x8*)&As[PL + idx];
        af[2][mi] = *(const s16x8*)&As[2*PL + idx];
      }
      #pragma unroll
      for (int ni=0; ni<4; ni++){
        int ct = wn*4 + ni;
        size_t idx = (size_t)ct*2048 + (size_t)(kc*4+lk)*128 + (size_t)lr*8;
        bf[0][ni] = *(const s16x8*)&Wp[idx];
        bf[1][ni] = *(const s16x8*)&Wp[16384 + idx];
        bf[2][ni] = *(const s16x8*)&Wp[32768 + idx];
      }
      #define TRM(sa,sb) \
        _Pragma("unroll") \
        for (int ni=0; ni<4; ni++){ \
          _Pragma("unroll") \
          for (int mi=0; mi<2; mi++){ \
            acc[mi][ni] = __builtin_amdgcn_mfma_f32_16x16x32_bf16(af[sa][mi], bf[sb][ni], acc[mi][ni], 0,0,0); \
          } \
        }
      TRM(0,0) TRM(0,1) TRM(1,0) TRM(1,1) TRM(0,2) TRM(2,0)
      #undef TRM
    }
  }

  float nrm = *norm_p;
  float pwv[4], biasv[4];
  #pragma unroll
  for (int ni=0;ni<4;ni++){
    int col = wn*64 + ni*16 + lr;
    pwv[ni] = pw[col]; biasv[ni] = bias[col];
  }
  #pragma unroll
  for (int mi=0; mi<2; mi++){
    #pragma unroll
    for (int reg=0; reg<4; reg++){
      int rl = wm*32 + mi*16 + lk*4 + reg;
      int row = m0 + rl;
      float hv[4]; float sc = 0.f;
      #pragma unroll
      for (int ni=0; ni<4; ni++){
        hv[ni] = fmaxf(acc[mi][ni][reg] + biasv[ni], 0.f);
        sc += hv[ni]*pwv[ni];
      }
      if (row < M){
        #pragma unroll
        for (int ni=0; ni<4; ni++)
          hout[(size_t)row*Hc + wn*64 + ni*16 + lr] = hv[ni];
      }
      sc += __shfl_xor(sc,1); sc += __shfl_xor(sc,2);
      sc += __shfl_xor(sc,4); sc += __shfl_xor(sc,8);
      if (lr == 0) scds[rl][wn] = sc;
    }
  }
  __syncthreads();
  if (tid < 64){
    int row = m0 + tid;
    if (row < M) score[row] = tanhf((scds[tid][0] + scds[tid][1]) / nrm);
  }
}

extern "C" void kernel_launch(void* const* d_in, const int* in_sizes, int n_in,
                              void* d_out, int out_size, void* d_ws, size_t ws_size,
                              hipStream_t stream){
  const float* x     = (const float*)d_in[0];
  const int*   esrc  = (const int*)d_in[1];
  const int*   edst  = (const int*)d_in[2];
  const float* Wrel1 = (const float*)d_in[5];
  const float* Wroot1= (const float*)d_in[6];
  const float* b1    = (const float*)d_in[7];
  const float* pw1   = (const float*)d_in[8];
  const float* Wrel2 = (const float*)d_in[9];
  const float* Wroot2= (const float*)d_in[10];
  const float* b2    = (const float*)d_in[11];
  const float* pw2   = (const float*)d_in[12];
  const float* Wrel3 = (const float*)d_in[13];
  const float* Wroot3= (const float*)d_in[14];
  const float* b3    = (const float*)d_in[15];
  const float* pw3   = (const float*)d_in[16];
  const float* Wl1   = (const float*)d_in[17];
  const float* bl1   = (const float*)d_in[18];
  const float* Wl2   = (const float*)d_in[19];
  const float* bl2   = (const float*)d_in[20];
  const float* Wl3   = (const float*)d_in[21];
  const float* bl3   = (const float*)d_in[22];
  float* out = (float*)d_out;

  char* ws = (char*)d_ws;
  size_t off = 0;
  auto alloc = [&](size_t elems)->void*{
    void* p = ws + off;
    off += ((elems*4 + 255)/256)*256;
    return p;
  };
  int*   deg    = (int*)alloc(N0);
  int*   rowptr = (int*)alloc(N0);
  int*   csr    = (int*)alloc(NE);
  int*   map1   = (int*)alloc(N0);
  int*   newid2 = (int*)alloc(N1);
  int*   map2   = (int*)alloc(N0);
  int*   perm1  = (int*)alloc(N1);
  int*   perm2  = (int*)alloc(N2);
  int*   perm3  = (int*)alloc(N3);
  int*   orig3  = (int*)alloc(N2);
  float* score1 = (float*)alloc(N0);
  float* score2 = (float*)alloc(N1);
  float* score3 = (float*)alloc(N2);
  float* xp     = (float*)alloc((size_t)N0*16);
  float* Wl1T   = (float*)alloc(256*512);
  float* Wl2T   = (float*)alloc(512*64);
  unsigned short* Wsp = (unsigned short*)alloc(98304);   // 196608 bf16
  unsigned short* W1S = (unsigned short*)alloc(6144);    // 12288 bf16
  float* norms  = (float*)alloc(3);
  float* bigA   = (float*)alloc((size_t)N0*Hc);      // h1, then aggS (3 planes)
  float* hB     = (float*)alloc((size_t)N1*Hc);      // h2 -> h3
  float* hpA    = (float*)alloc((size_t)N1*Hc);      // hp f32 row-major
  unsigned short* hpS = (unsigned short*)alloc((size_t)3*N1*Hc/2);  // 3 planes, frag layout
  float* z      = (float*)alloc(BG*256);

  float* h1   = bigA;
  unsigned short* aggS = (unsigned short*)bigA;   // h1 dead by then
  unsigned short* a1S  = hpS;                     // dead before topg fills hpS
  float* h2   = hB;
  float* h3   = hB;

  // front: CSR + weight prep + z zero + norms + x pack (one launch)
  k_front<<<3656, 512, 0, stream>>>(esrc, edst, x,
                                    Wrel1, Wroot1, Wrel2, Wroot2, Wrel3, Wroot3,
                                    Wl1, Wl2, pw1, pw2, pw3,
                                    deg, rowptr, csr, xp,
                                    Wl1T, Wl2T, Wsp, W1S, z, norms);

  // layer 1
  k_agg1s  <<<N0/4, 256, 0, stream>>>(xp, csr, rowptr, deg, a1S);
  k_conv1m <<<N0/64, 256, 0, stream>>>(a1S, W1S, b1, pw1, norms+0, h1, score1, N0);
  k_topg<NPGc, K1c, 512, true, false><<<BG, 1024, 0, stream>>>(
      score1, h1, map1, perm1, nullptr, nullptr, nullptr, nullptr,
      hpA, hpS, z, nullptr, nullptr, nullptr, nullptr, nullptr, nullptr, nullptr);

  // layer 2
  k_aggHs  <<<N1/4, 256, 0, stream>>>(perm1, map1, hpA, csr, rowptr, deg, aggS, N1);
  k_convH  <<<N1/64, 256, 0, stream>>>(aggS, hpS, Wsp, b2, pw2, norms+1, h2, score2, N1);
  k_topg<K1c, K2c, 256, true, false><<<BG, 1024, 0, stream>>>(
      score2, h2, newid2, perm2, map1, map2, perm1, orig3,
      hpA, hpS, z, nullptr, nullptr, nullptr, nullptr, nullptr, nullptr, nullptr);

  // layer 3  (grid padded to x8 for bijective XCD swizzle)
  k_aggHs  <<<10256, 256, 0, stream>>>(orig3, map2, hpA, csr, rowptr, deg, aggS, N2);
  k_convH  <<<(N2+63)/64, 256, 0, stream>>>(aggS, hpS, Wsp + 98304, b3, pw3, norms+2,
                                            h3, score3, N2);
  k_topg<K2c, K3c, 256, false, true><<<BG, 1024, 0, stream>>>(
      score3, h3, newid2, perm3, nullptr, nullptr, nullptr, nullptr,
      nullptr, nullptr, z, Wl1T, bl1, Wl2T, bl2, Wl3, bl3, out);
}